// Round 12
// baseline (179.780 us; speedup 1.0000x reference)
//
#include <hip/hip_runtime.h>

#define NPOS 589824   // 64*96*96
#define LN_EPS 1e-5f

typedef _Float16 half8 __attribute__((ext_vector_type(8)));
typedef float f32x4 __attribute__((ext_vector_type(4)));
typedef float f32x2 __attribute__((ext_vector_type(2)));

#define GR_BLOCKS 1152
#define TILE 128
#define CPB 4          // 1152 * 4 * 128 == NPOS
#define YSTR 136

// ws (bytes): [0,16K) G/M/beta ; [16K, +4.72M) stats ; then partials 2.65M.
// Total 7.39 MB == R9's proven-fitting footprint.

// Pass 1: rolling-stream LN stats (R9 pattern, ~6 TB/s). 4 pos/thread, f32x4.
__global__ __launch_bounds__(256) void csa_stats(
    const float* __restrict__ x, float* __restrict__ stats)
{
    const int g = blockIdx.x * 256 + threadIdx.x;        // 0 .. NPOS/4-1
    const f32x4* __restrict__ x4 = (const f32x4*)x;
    f32x4 s = {0.f,0.f,0.f,0.f}, sq = s;
    #pragma unroll
    for (int c = 0; c < 64; ++c) {
        f32x4 v = x4[(size_t)c * (NPOS/4) + g];
        s += v;
        sq += v * v;
    }
    const f32x4 mu = s * (1.f/64.f);
    const f32x4 var = sq * (1.f/64.f) - mu * mu;
    f32x4 o0, o1;
    o0[0] = mu[0]; o0[2] = mu[1]; o1[0] = mu[2]; o1[2] = mu[3];
    o0[1] = rsqrtf(fmaxf(var[0], 0.f) + LN_EPS);
    o0[3] = rsqrtf(fmaxf(var[1], 0.f) + LN_EPS);
    o1[1] = rsqrtf(fmaxf(var[2], 0.f) + LN_EPS);
    o1[3] = rsqrtf(fmaxf(var[3], 0.f) + LN_EPS);
    f32x4* st4 = (f32x4*)stats;
    st4[2*g]     = o0;
    st4[2*g + 1] = o1;
}

// Pass 2: Gram via global_load_lds DMA staging (zero-VGPR loads, deep queue).
// Per tile: 22 DMA instrs stage ch 0..43 (f32) into XT[44][128]; barrier;
// y = LN(XT) -> f16 Y tile; barrier; R11-verified MFMA (K=128, wave wv owns
// K slice [wv*32, wv*32+32)). 4 tiles per block.
__global__ __launch_bounds__(256, 4) void csa_gram(
    const float* __restrict__ x, const float* __restrict__ lng,
    const float* __restrict__ lnb, const float* __restrict__ stats,
    float* __restrict__ partials)
{
    __shared__ __align__(16) float XT[44][TILE];      // 22528 B (raw x)
    __shared__ __align__(16) _Float16 Y[45][YSTR];    // 12240 B
    const int tid = threadIdx.x;
    const int lane = tid & 63;
    const int wv = tid >> 6;
    const int p = tid & 127;                          // position in tile
    const int cbase = (tid >> 7) * 22;                // 0 or 22 (wave-uniform)

    for (int i = tid; i < YSTR; i += 256) {
        Y[43][i] = (_Float16)1.0f;
        Y[44][i] = (_Float16)0.0f;
    }

    f32x4 acc00 = {0.f,0.f,0.f,0.f}, acc01 = acc00, acc10 = acc00, acc11 = acc00;
    const int row = lane & 15;
    const int sub = (lane >> 4) & 3;
    const int kk = wv * 32 + sub * 8;
    const int r16 = row + 16;
    const int ra1 = (r16 < 22) ? r16 : ((r16 == 22) ? 43 : 44);
    const int rb1 = (r16 < 22) ? (r16 + 21) : ((r16 == 22) ? 43 : 44);
    const int pos0 = blockIdx.x * (CPB * TILE);
    const int rhalf = lane >> 5;                      // 0/1: row within pair
    const int cq = lane & 31;                         // 16B quad within row

    for (int ck = 0; ck < CPB; ++ck) {
        const int n0 = pos0 + ck * TILE;
        // --- DMA stage: pair i covers channels 2i, 2i+1 (1 KB -> XT) ---
        #pragma unroll
        for (int j = 0; j < 6; ++j) {
            const int i = wv * 6 + j;
            if (i < 22) {
                const float* g = x + (size_t)(2*i + rhalf) * NPOS + n0 + cq * 4;
                __builtin_amdgcn_global_load_lds(g, &XT[2*i][0], 16, 0, 0);
            }
        }
        __syncthreads();                              // drains vmcnt
        // --- LN: y from XT + stats ---
        const f32x2 st = ((const f32x2*)stats)[n0 + p];
        const float mu = st[0], rin = st[1];
        #pragma unroll
        for (int k = 0; k < 22; ++k) {
            const int c = cbase + k;
            if (c < 43)
                Y[c][p] = (_Float16)fmaf((XT[c][p] - mu) * rin, lng[c], lnb[c]);
        }
        __syncthreads();
        // --- MFMA (R11-verified mapping) ---
        half8 a0 = *(const half8*)&Y[row][kk];
        half8 a1 = *(const half8*)&Y[ra1][kk];
        half8 b0 = *(const half8*)&Y[row + 21][kk];
        half8 b1 = *(const half8*)&Y[rb1][kk];
        acc00 = __builtin_amdgcn_mfma_f32_16x16x32_f16(a0, b0, acc00, 0, 0, 0);
        acc01 = __builtin_amdgcn_mfma_f32_16x16x32_f16(a0, b1, acc01, 0, 0, 0);
        acc10 = __builtin_amdgcn_mfma_f32_16x16x32_f16(a1, b0, acc10, 0, 0, 0);
        acc11 = __builtin_amdgcn_mfma_f32_16x16x32_f16(a1, b1, acc11, 0, 0, 0);
        __syncthreads();                              // Y/XT safe to overwrite
    }

    // block reduce (reuse XT as float scratch)
    float* G32 = (float*)&XT[0][0];
    for (int e = tid; e < 1024; e += 256) G32[e] = 0.f;
    __syncthreads();
    const int r0 = (lane >> 4) * 4, cc = lane & 15;
    #pragma unroll
    for (int r = 0; r < 4; ++r) {
        atomicAdd(&G32[(r0 + r) * 32 + cc],            acc00[r]);
        atomicAdd(&G32[(r0 + r) * 32 + 16 + cc],       acc01[r]);
        atomicAdd(&G32[(16 + r0 + r) * 32 + cc],       acc10[r]);
        atomicAdd(&G32[(16 + r0 + r) * 32 + 16 + cc],  acc11[r]);
    }
    __syncthreads();
    for (int e = tid; e < 576; e += 256) {            // used 24x24 corner
        const int r = e / 24, c = e % 24;
        partials[(size_t)blockIdx.x * 576 + e] = G32[r * 32 + c];
    }
}

__global__ __launch_bounds__(256) void csa_k2(const float* __restrict__ partials,
                                              float* __restrict__ gfin)
{
    const int tid = threadIdx.x;
    const int e = blockIdx.x * 16 + (tid >> 4);       // 36 blocks * 16 = 576
    const int g = tid & 15;
    float s = 0.f;
    for (int b = g; b < GR_BLOCKS; b += 16)
        s += partials[(size_t)b * 576 + e];
    s += __shfl_down(s, 8, 16);
    s += __shfl_down(s, 4, 16);
    s += __shfl_down(s, 2, 16);
    s += __shfl_down(s, 1, 16);
    if (g == 0) gfin[e] = s;
}

__global__ void csa_k3(const float* __restrict__ G, const float* __restrict__ cw,
                       const float* __restrict__ cb, float* __restrict__ M,
                       float* __restrict__ betaO)
{
    const int c = threadIdx.x;
    __shared__ float lg[64][65];
    const float wq = cw[c], bq = cb[c];
    const int a = c / 3;
    const float Sa = G[a * 24 + 22];
    float mx = -1e30f;
    #pragma unroll
    for (int k = 0; k < 64; ++k) {
        const float wk = cw[64 + k], bk = cb[64 + k];
        const int b = (64 + k) / 3 - 21;
        const float Gab = G[a * 24 + b];
        const float Sb  = G[22 * 24 + b];
        float lo = 0.125f * (wq * wk * Gab + wq * bk * Sa + bq * wk * Sb
                             + bq * bk * (float)NPOS);
        lg[c][k] = lo;
        mx = fmaxf(mx, lo);
    }
    float sum = 0.f;
    #pragma unroll
    for (int k = 0; k < 64; ++k) {
        float e = expf(lg[c][k] - mx);
        lg[c][k] = e; sum += e;
    }
    const float inv = 1.f / sum;
    float Ml[22];
    #pragma unroll
    for (int m = 0; m < 22; ++m) Ml[m] = 0.f;
    float bacc = 0.f;
    #pragma unroll
    for (int k = 0; k < 64; ++k) {
        const float attn = lg[c][k] * inv;
        const int mm = (128 + k) / 3 - 42;
        Ml[mm] = fmaf(attn, cw[128 + k], Ml[mm]);
        bacc   = fmaf(attn, cb[128 + k], bacc);
    }
    #pragma unroll
    for (int m = 0; m < 22; ++m) M[c * 22 + m] = Ml[m];
    betaO[c] = bacc;
}

// Pass 3: output, stats-fed streaming (no xv[64] parking). Phase A: y[22]
// from ch 42..63. Phase B: stream all 64 channels (42..63 re-hit L1/L2),
// out = x + M.y, nontemporal f32x2 stores.
__global__ __launch_bounds__(256, 4) void csa_k4(
    const float* __restrict__ x, const float* __restrict__ lng,
    const float* __restrict__ lnb, const float* __restrict__ stats,
    const float* __restrict__ M, const float* __restrict__ betaO,
    float* __restrict__ out)
{
    const int gt = blockIdx.x * 256 + threadIdx.x;
    const int n0 = gt * 2;
    const f32x4 st = ((const f32x4*)stats)[gt];       // mu0,rin0,mu1,rin1
    const float mu0 = st[0], rin0 = st[1], mu1 = st[2], rin1 = st[3];
    f32x2 y[22];
    #pragma unroll
    for (int m = 0; m < 22; ++m) {
        f32x2 v = *(const f32x2*)(x + (size_t)(42 + m) * NPOS + n0);
        const float g = lng[42 + m], b = lnb[42 + m];
        y[m][0] = fmaf((v[0] - mu0) * rin0, g, b);
        y[m][1] = fmaf((v[1] - mu1) * rin1, g, b);
    }
    #pragma unroll
    for (int c = 0; c < 64; ++c) {
        f32x2 v = *(const f32x2*)(x + (size_t)c * NPOS + n0);
        const float bb = betaO[c];
        f32x2 a = {bb, bb};
        #pragma unroll
        for (int m = 0; m < 22; ++m) {
            const float w = M[c * 22 + m];            // uniform -> scalar
            a[0] = fmaf(w, y[m][0], a[0]);
            a[1] = fmaf(w, y[m][1], a[1]);
        }
        f32x2 o = v + a;
        __builtin_nontemporal_store(o, (f32x2*)(out + (size_t)c * NPOS + n0));
    }
}

extern "C" void kernel_launch(void* const* d_in, const int* in_sizes, int n_in,
                              void* d_out, int out_size, void* d_ws, size_t ws_size,
                              hipStream_t stream) {
    const float* x   = (const float*)d_in[0];
    const float* lng = (const float*)d_in[1];
    const float* lnb = (const float*)d_in[2];
    const float* cw  = (const float*)d_in[3];
    const float* cb  = (const float*)d_in[4];
    float* out = (float*)d_out;

    float* wsf   = (float*)d_ws;
    float* Gf    = wsf;                                // 576 used
    float* Mf    = wsf + 1024;                         // 64*22
    float* Bf    = wsf + 1024 + 64 * 22;               // 64
    float* stats = (float*)((char*)d_ws + 16384);      // NPOS*2 f = 4.72 MB
    float* Pf    = (float*)((char*)d_ws + 16384 + (size_t)NPOS * 8); // 2.65 MB

    hipLaunchKernelGGL(csa_stats, dim3(NPOS / 1024), dim3(256), 0, stream,
                       x, stats);
    hipLaunchKernelGGL(csa_gram, dim3(GR_BLOCKS), dim3(256), 0, stream,
                       x, lng, lnb, stats, Pf);
    hipLaunchKernelGGL(csa_k2, dim3(36), dim3(256), 0, stream, Pf, Gf);
    hipLaunchKernelGGL(csa_k3, dim3(1), dim3(64), 0, stream, Gf, cw, cb, Mf, Bf);
    hipLaunchKernelGGL(csa_k4, dim3(NPOS / 512), dim3(256), 0, stream,
                       x, lng, lnb, stats, Mf, Bf, out);
}

// Round 13
// 174.311 us; speedup vs baseline: 1.0314x; 1.0314x over previous
//
#include <hip/hip_runtime.h>

#define NPOS 589824   // 64*96*96
#define LN_EPS 1e-5f

typedef _Float16 half8 __attribute__((ext_vector_type(8)));
typedef float f32x4 __attribute__((ext_vector_type(4)));
typedef float f32x2 __attribute__((ext_vector_type(2)));

#define GR_BLOCKS 1152
#define TILE 128
#define YSTR 136

// ws (bytes): [0,16K) M/beta ; [16K, +4.72M) stats ; then partials 2.65M.

// Pass 1: rolling-stream LN stats (no barriers, proven pattern).
__global__ __launch_bounds__(256) void csa_stats(
    const float* __restrict__ x, float* __restrict__ stats)
{
    const int g = blockIdx.x * 256 + threadIdx.x;        // 0 .. NPOS/4-1
    const f32x4* __restrict__ x4 = (const f32x4*)x;
    f32x4 s = {0.f,0.f,0.f,0.f}, sq = s;
    #pragma unroll
    for (int c = 0; c < 64; ++c) {
        f32x4 v = x4[(size_t)c * (NPOS/4) + g];
        s += v;
        sq += v * v;
    }
    const f32x4 mu = s * (1.f/64.f);
    const f32x4 var = sq * (1.f/64.f) - mu * mu;
    f32x4 o0, o1;
    o0[0] = mu[0]; o0[2] = mu[1]; o1[0] = mu[2]; o1[2] = mu[3];
    o0[1] = rsqrtf(fmaxf(var[0], 0.f) + LN_EPS);
    o0[3] = rsqrtf(fmaxf(var[1], 0.f) + LN_EPS);
    o1[1] = rsqrtf(fmaxf(var[2], 0.f) + LN_EPS);
    o1[3] = rsqrtf(fmaxf(var[3], 0.f) + LN_EPS);
    f32x4* st4 = (f32x4*)stats;
    st4[2*g]     = o0;
    st4[2*g + 1] = o1;
}

// Pass 2: Gram with T3/T4 pipeline: double-buffered global_load_lds staging,
// counted vmcnt(6) (never 0 in-loop), raw s_barrier. Only DMA ops touch vmcnt
// inside the loop (stats preloaded to regs, lng/lnb to LDS, drained upfront).
__global__ __launch_bounds__(256, 2) void csa_gram(
    const float* __restrict__ x, const float* __restrict__ lng,
    const float* __restrict__ lnb, const float* __restrict__ stats,
    float* __restrict__ partials)
{
    __shared__ __align__(16) float XT[2][48][TILE];   // 49152 B (raw x)
    __shared__ __align__(16) _Float16 Y[45][YSTR];    // 12240 B
    __shared__ float Lg[43], Lb[43];                  // 344 B
    const int tid = threadIdx.x;
    const int lane = tid & 63;
    const int wv = tid >> 6;
    const int p = tid & 127;
    const int cbase = (tid >> 7) * 22;                // 0 or 22
    const int rhalf = lane >> 5;
    const int cq = lane & 31;
    const int pos0 = blockIdx.x * (4 * TILE);

    if (tid < 43) { Lg[tid] = lng[tid]; Lb[tid] = lnb[tid]; }
    for (int i = tid; i < YSTR; i += 256) {
        Y[43][i] = (_Float16)1.0f;
        Y[44][i] = (_Float16)0.0f;
    }
    float mu_[4], rin_[4];                            // stats upfront
    #pragma unroll
    for (int ck = 0; ck < 4; ++ck) {
        f32x2 st = ((const f32x2*)stats)[pos0 + ck * TILE + p];
        mu_[ck] = st[0]; rin_[ck] = st[1];
    }
    asm volatile("s_waitcnt vmcnt(0)" ::: "memory");  // only DMA in vmcnt now
    __builtin_amdgcn_sched_barrier(0);

    f32x4 acc00 = {0.f,0.f,0.f,0.f}, acc01 = acc00, acc10 = acc00, acc11 = acc00;
    const int row = lane & 15;
    const int sub = (lane >> 4) & 3;
    const int kk = wv * 32 + sub * 8;
    const int r16 = row + 16;
    const int ra1 = (r16 < 22) ? r16 : ((r16 == 22) ? 43 : 44);
    const int rb1 = (r16 < 22) ? (r16 + 21) : ((r16 == 22) ? 43 : 44);

    // 24 pairs = 48 rows (pairs 22,23 duplicate 0,1 so each wave issues 6).
    #define STAGE(B, CK)                                                       \
      { _Pragma("unroll")                                                      \
        for (int j = 0; j < 6; ++j) {                                          \
            const int pr = wv * 6 + j;                                         \
            const int ch = (pr < 22) ? (2*pr + rhalf) : (2*(pr-22) + rhalf);   \
            __builtin_amdgcn_global_load_lds(                                  \
                x + (size_t)ch * NPOS + pos0 + (CK) * TILE + cq * 4,           \
                &XT[B][2*pr][0], 16, 0, 0);                                    \
        } }

    #define LNPH(B, CK)                                                        \
      { const float mu = mu_[CK], rin = rin_[CK];                              \
        _Pragma("unroll")                                                      \
        for (int k2 = 0; k2 < 22; ++k2) {                                      \
            const int c = cbase + k2;                                          \
            if (c < 43)                                                        \
                Y[c][p] = (_Float16)fmaf((XT[B][c][p] - mu) * rin,             \
                                         Lg[c], Lb[c]);                        \
        } }

    #define MM()                                                               \
      { half8 a0 = *(const half8*)&Y[row][kk];                                 \
        half8 a1 = *(const half8*)&Y[ra1][kk];                                 \
        half8 b0 = *(const half8*)&Y[row + 21][kk];                            \
        half8 b1 = *(const half8*)&Y[rb1][kk];                                 \
        acc00 = __builtin_amdgcn_mfma_f32_16x16x32_f16(a0, b0, acc00, 0, 0, 0);\
        acc01 = __builtin_amdgcn_mfma_f32_16x16x32_f16(a0, b1, acc01, 0, 0, 0);\
        acc10 = __builtin_amdgcn_mfma_f32_16x16x32_f16(a1, b0, acc10, 0, 0, 0);\
        acc11 = __builtin_amdgcn_mfma_f32_16x16x32_f16(a1, b1, acc11, 0, 0, 0);}

    #define WAIT6  asm volatile("s_waitcnt vmcnt(6) lgkmcnt(0)" ::: "memory"); \
                   __builtin_amdgcn_sched_barrier(0);                          \
                   __builtin_amdgcn_s_barrier();                               \
                   __builtin_amdgcn_sched_barrier(0);
    #define WAIT0  asm volatile("s_waitcnt vmcnt(0) lgkmcnt(0)" ::: "memory"); \
                   __builtin_amdgcn_sched_barrier(0);                          \
                   __builtin_amdgcn_s_barrier();                               \
                   __builtin_amdgcn_sched_barrier(0);
    #define LGKMB  asm volatile("s_waitcnt lgkmcnt(0)" ::: "memory");          \
                   __builtin_amdgcn_sched_barrier(0);                          \
                   __builtin_amdgcn_s_barrier();                               \
                   __builtin_amdgcn_sched_barrier(0);

    STAGE(0, 0)                                       // prologue
    // chunk 0
    STAGE(1, 1)
    WAIT6
    LNPH(0, 0)
    LGKMB
    MM()
    __builtin_amdgcn_s_barrier();
    __builtin_amdgcn_sched_barrier(0);
    // chunk 1
    STAGE(0, 2)
    WAIT6
    LNPH(1, 1)
    LGKMB
    MM()
    __builtin_amdgcn_s_barrier();
    __builtin_amdgcn_sched_barrier(0);
    // chunk 2
    STAGE(1, 3)
    WAIT6
    LNPH(0, 2)
    LGKMB
    MM()
    __builtin_amdgcn_s_barrier();
    __builtin_amdgcn_sched_barrier(0);
    // chunk 3 (drain)
    WAIT0
    LNPH(1, 3)
    LGKMB
    MM()
    __syncthreads();                                  // no DMA left; safe

    // block reduce (reuse XT as float scratch)
    float* G32 = (float*)&XT[0][0][0];
    for (int e = tid; e < 1024; e += 256) G32[e] = 0.f;
    __syncthreads();
    const int r0 = (lane >> 4) * 4, cc = lane & 15;
    #pragma unroll
    for (int r = 0; r < 4; ++r) {
        atomicAdd(&G32[(r0 + r) * 32 + cc],            acc00[r]);
        atomicAdd(&G32[(r0 + r) * 32 + 16 + cc],       acc01[r]);
        atomicAdd(&G32[(16 + r0 + r) * 32 + cc],       acc10[r]);
        atomicAdd(&G32[(16 + r0 + r) * 32 + 16 + cc],  acc11[r]);
    }
    __syncthreads();
    for (int e = tid; e < 576; e += 256) {            // used 24x24 corner
        const int r = e / 24, c = e % 24;
        partials[(size_t)blockIdx.x * 576 + e] = G32[r * 32 + c];
    }
}

// Pass 2b: partial-reduce + softmax + M/beta in ONE kernel (1024 threads).
__global__ __launch_bounds__(1024) void csa_fin(
    const float* __restrict__ partials, const float* __restrict__ cw,
    const float* __restrict__ cb, float* __restrict__ M,
    float* __restrict__ betaO)
{
    __shared__ float Gs[576];
    __shared__ float lg[64][65];
    const int tid = threadIdx.x;
    if (tid < 576) {
        float s = 0.f;
        for (int b = 0; b < GR_BLOCKS; b += 8) {      // 8-deep MLP
            float t0 = partials[(size_t)(b+0)*576 + tid];
            float t1 = partials[(size_t)(b+1)*576 + tid];
            float t2 = partials[(size_t)(b+2)*576 + tid];
            float t3 = partials[(size_t)(b+3)*576 + tid];
            float t4 = partials[(size_t)(b+4)*576 + tid];
            float t5 = partials[(size_t)(b+5)*576 + tid];
            float t6 = partials[(size_t)(b+6)*576 + tid];
            float t7 = partials[(size_t)(b+7)*576 + tid];
            s += ((t0+t1)+(t2+t3)) + ((t4+t5)+(t6+t7));
        }
        Gs[tid] = s;
    }
    __syncthreads();
    if (tid < 64) {
        const int c = tid;
        const float wq = cw[c], bq = cb[c];
        const int a = c / 3;
        const float Sa = Gs[a * 24 + 22];
        float mx = -1e30f;
        #pragma unroll
        for (int k = 0; k < 64; ++k) {
            const float wk = cw[64 + k], bk = cb[64 + k];
            const int b = (64 + k) / 3 - 21;
            const float Gab = Gs[a * 24 + b];
            const float Sb  = Gs[22 * 24 + b];
            float lo = 0.125f * (wq * wk * Gab + wq * bk * Sa + bq * wk * Sb
                                 + bq * bk * (float)NPOS);
            lg[c][k] = lo;
            mx = fmaxf(mx, lo);
        }
        float sum = 0.f;
        #pragma unroll
        for (int k = 0; k < 64; ++k) {
            float e = expf(lg[c][k] - mx);
            lg[c][k] = e; sum += e;
        }
        const float inv = 1.f / sum;
        float Ml[22];
        #pragma unroll
        for (int m = 0; m < 22; ++m) Ml[m] = 0.f;
        float bacc = 0.f;
        #pragma unroll
        for (int k = 0; k < 64; ++k) {
            const float attn = lg[c][k] * inv;
            const int mm = (128 + k) / 3 - 42;
            Ml[mm] = fmaf(attn, cw[128 + k], Ml[mm]);
            bacc   = fmaf(attn, cb[128 + k], bacc);
        }
        #pragma unroll
        for (int m = 0; m < 22; ++m) M[c * 22 + m] = Ml[m];
        betaO[c] = bacc;
    }
}

// Pass 3: output, stats-fed streaming.
__global__ __launch_bounds__(256, 4) void csa_k4(
    const float* __restrict__ x, const float* __restrict__ lng,
    const float* __restrict__ lnb, const float* __restrict__ stats,
    const float* __restrict__ M, const float* __restrict__ betaO,
    float* __restrict__ out)
{
    const int gt = blockIdx.x * 256 + threadIdx.x;
    const int n0 = gt * 2;
    const f32x4 st = ((const f32x4*)stats)[gt];       // mu0,rin0,mu1,rin1
    const float mu0 = st[0], rin0 = st[1], mu1 = st[2], rin1 = st[3];
    f32x2 y[22];
    #pragma unroll
    for (int m = 0; m < 22; ++m) {
        f32x2 v = *(const f32x2*)(x + (size_t)(42 + m) * NPOS + n0);
        const float g = lng[42 + m], b = lnb[42 + m];
        y[m][0] = fmaf((v[0] - mu0) * rin0, g, b);
        y[m][1] = fmaf((v[1] - mu1) * rin1, g, b);
    }
    #pragma unroll
    for (int c = 0; c < 64; ++c) {
        f32x2 v = *(const f32x2*)(x + (size_t)c * NPOS + n0);
        const float bb = betaO[c];
        f32x2 a = {bb, bb};
        #pragma unroll
        for (int m = 0; m < 22; ++m) {
            const float w = M[c * 22 + m];
            a[0] = fmaf(w, y[m][0], a[0]);
            a[1] = fmaf(w, y[m][1], a[1]);
        }
        f32x2 o = v + a;
        __builtin_nontemporal_store(o, (f32x2*)(out + (size_t)c * NPOS + n0));
    }
}

extern "C" void kernel_launch(void* const* d_in, const int* in_sizes, int n_in,
                              void* d_out, int out_size, void* d_ws, size_t ws_size,
                              hipStream_t stream) {
    const float* x   = (const float*)d_in[0];
    const float* lng = (const float*)d_in[1];
    const float* lnb = (const float*)d_in[2];
    const float* cw  = (const float*)d_in[3];
    const float* cb  = (const float*)d_in[4];
    float* out = (float*)d_out;

    float* wsf   = (float*)d_ws;
    float* Mf    = wsf + 1024;                         // 64*22
    float* Bf    = wsf + 1024 + 64 * 22;               // 64
    float* stats = (float*)((char*)d_ws + 16384);      // NPOS*2 f = 4.72 MB
    float* Pf    = (float*)((char*)d_ws + 16384 + (size_t)NPOS * 8); // 2.65 MB

    hipLaunchKernelGGL(csa_stats, dim3(NPOS / 1024), dim3(256), 0, stream,
                       x, stats);
    hipLaunchKernelGGL(csa_gram, dim3(GR_BLOCKS), dim3(256), 0, stream,
                       x, lng, lnb, stats, Pf);
    hipLaunchKernelGGL(csa_fin, dim3(1), dim3(1024), 0, stream,
                       Pf, cw, cb, Mf, Bf);
    hipLaunchKernelGGL(csa_k4, dim3(NPOS / 512), dim3(256), 0, stream,
                       x, lng, lnb, stats, Mf, Bf, out);
}